// Round 8
// baseline (292.876 us; speedup 1.0000x reference)
//
#include <hip/hip_runtime.h>

// Problem constants (fixed by setup_inputs)
constexpr int Bc = 2, Dc = 48, Hc = 512, Wc = 640;
constexpr int HWc = Hc * Wc;

// Tile: 32x16 spatial, 256 threads, 2 consecutive-w pixels per thread.
// DSPLIT=1, DC=2 (R3 structure, best measured). This round:
//  - depth-2 register prefetch (pA/pB): interval iv issues loads for iv+2,
//    commit consumes loads issued 2 phases earlier -> 2x in-flight bytes.
//  - drain-free barriers: s_waitcnt lgkmcnt(0) + raw s_barrier instead of
//    __syncthreads(), so prefetch loads (register-destined) and output
//    stores stay in flight across the barrier. LDS-write visibility is all
//    the barrier must order -> lgkmcnt(0) suffices.
//  - R7 BUG FIXED: issue/compute take an INTERVAL index and scale by DC
//    internally (R7 passed interval indices into a d-plane-scaled base,
//    reading only planes 0..24 and never writing planes 25..47).
constexpr int TW = 32, TH = 16, NT = 256;
constexpr int NXT = Wc / TW;                  // 20 tiles in w
constexpr int NYT = Hc / TH;                  // 32 tiles in h
constexpr int NBLK = NXT * NYT * Bc;          // 1280 blocks = 5.0/CU
constexpr int NXCD = 8;
constexpr int BPX = NBLK / NXCD;              // 160 blocks per XCD
constexpr int HALO = 4;                       // far taps reach +/-4
constexpr int SW = TW + 2 * HALO;             // 40
constexpr int SH = TH + 2 * HALO;             // 24
constexpr int PLANE = SW * SH;                // 960 floats/plane
constexpr int DC = 2;                         // d-planes per barrier interval
constexpr int NIT = Dc / DC;                  // 24 intervals (even: 2x unroll)
constexpr int NVEC = DC * PLANE / 4;          // 480 float4 per interval
constexpr int VPT = (NVEC + NT - 1) / NT;     // 2

__device__ __forceinline__ int reflect_h(int h) {
    return h < 0 ? -h : (h >= Hc ? 2 * (Hc - 1) - h : h);
}
__device__ __forceinline__ int reflect_w(int w) {
    return w < 0 ? -w : (w >= Wc ? 2 * (Wc - 1) - w : w);
}

// VGPR target <=64; NO waves-per-EU hint (R4: forcing it spilled to scratch).
// XCD-contiguous swizzle: hardware round-robins blockIdx%8 across XCDs;
// logical = (hw%8)*160 + hw/8 gives each XCD a contiguous 20x8 tile band so
// halo lines shared between neighbor tiles hit the same 4MB L2 (R3: FETCH
// 287->87MB from this).
__global__ __launch_bounds__(NT) void dw_kernel(
    const float* __restrict__ ds, const float* __restrict__ dmin,
    const float* __restrict__ dmax, const float* __restrict__ off,
    const float* __restrict__ scale_p, float* __restrict__ out)
{
    __shared__ float sx[2][DC * PLANE];       // double-buffered (15360 B)

    const int hw  = blockIdx.x;
    const int l   = (hw & (NXCD - 1)) * BPX + (hw >> 3);   // XCD-contiguous
    const int bx  = l % NXT;
    const int rem = l / NXT;
    const int by  = rem % NYT;
    const int b   = rem / NYT;
    const int h0  = by * TH;
    const int w0  = bx * TW;
    const int tid = threadIdx.x;
    const int col = tid & 15;                 // 16 float2-groups across 32 w
    const int row = tid >> 4;                 // 0..15

    const float inv_min   = 1.0f / dmin[b];
    const float inv_max   = 1.0f / dmax[b];
    const float invd      = 1.0f / (inv_min - inv_max);
    const float nmc       = -inv_max * invd;  // x = fma(rcp(v), invd, nmc)
    const float inv_scale = 1.0f / scale_p[0];

    // 18 offset channels x 2 pixels -> 36 registers, pre-scaled by 0.5
    // (folds the (f+f1)*0.5 into the weights; reused 48x).
    float offF[9][2], offN[9][2];
    {
        const float* op = off + (size_t)b * 18 * HWc
                        + (size_t)(h0 + row) * Wc + (w0 + 2 * col);
        #pragma unroll
        for (int s = 0; s < 9; ++s) {
            float2 vF = *(const float2*)(op + (size_t)s * HWc);
            float2 vN = *(const float2*)(op + (size_t)(s + 9) * HWc);
            offF[s][0] = 0.5f * vF.x; offF[s][1] = 0.5f * vF.y;
            offN[s][0] = 0.5f * vN.x; offN[s][1] = 0.5f * vN.y;
        }
    }

    const float* dsb  = ds  + (size_t)b * Dc * HWc;
    float*       outb = out + (size_t)b * Dc * HWc
                            + (size_t)(h0 + row) * Wc + (w0 + 2 * col);

    // d-invariant staging addresses: row base + column (column may be out of
    // range only for bx==0 (c0=-4) or bx==NXT-1 (c0=640) -> per-float4
    // reflect fallback; interior blocks take the vector path uniformly.
    int vsrc[VPT], vcol[VPT];
    #pragma unroll
    for (int i = 0; i < VPT; ++i) {
        int vid = tid + i * NT;
        if (vid < NVEC) {
            int p    = vid / (PLANE / 4);
            int rem2 = vid - p * (PLANE / 4);
            int r    = rem2 / (SW / 4);
            int j    = rem2 - r * (SW / 4);
            int hs   = reflect_h(h0 + r - HALO);
            vsrc[i]  = p * HWc + hs * Wc;
            vcol[i]  = w0 - HALO + 4 * j;
        } else { vsrc[i] = 0; vcol[i] = 0; }
    }

    float4 pA[VPT], pB[VPT];

    auto issue = [&](float4* pre, int iv) {   // loads only -> stay in flight
        const float* dp = dsb + (size_t)(iv * DC) * HWc;
        #pragma unroll
        for (int i = 0; i < VPT; ++i) {
            int vid = tid + i * NT;
            if (vid < NVEC) {
                const float* rp = dp + vsrc[i];
                int c0 = vcol[i];
                if (c0 >= 0 && c0 + 4 <= Wc) {
                    pre[i] = *(const float4*)(rp + c0);
                } else {                      // w-edge reflect (rare lanes)
                    float4 v;
                    v.x = rp[reflect_w(c0)];
                    v.y = rp[reflect_w(c0 + 1)];
                    v.z = rp[reflect_w(c0 + 2)];
                    v.w = rp[reflect_w(c0 + 3)];
                    pre[i] = v;
                }
            }
        }
    };
    auto commit = [&](const float4* pre, float* sb) {
        #pragma unroll
        for (int i = 0; i < VPT; ++i) {
            int vid = tid + i * NT;
            if (vid < NVEC) {
                float4 v = pre[i], x;
                x.x = fmaf(__builtin_amdgcn_rcpf(v.x), invd, nmc);
                x.y = fmaf(__builtin_amdgcn_rcpf(v.y), invd, nmc);
                x.z = fmaf(__builtin_amdgcn_rcpf(v.z), invd, nmc);
                x.w = fmaf(__builtin_amdgcn_rcpf(v.w), invd, nmc);
                *(float4*)(sb + vid * 4) = x;
            }
        }
    };

    // Drain-free barrier: LDS writes are the only thing the barrier must
    // order (ds op completion = lgkmcnt). Register prefetch loads and
    // global output stores stay in flight (no vmcnt drain).
    auto bar = [&]() {
        asm volatile("s_waitcnt lgkmcnt(0)" ::: "memory");
        __builtin_amdgcn_s_barrier();
    };

    // Stencil for one interval. Per plane: 17 ds_read_b64 feed 2 pixels.
    auto compute = [&](const float* sb, int iv) {
        #pragma unroll
        for (int p = 0; p < DC; ++p) {
            // bp -> this thread's center pixel (even word offset: b64 aligned)
            const float* bp = sb + p * PLANE + (row + HALO) * SW + (HALO + 2 * col);
            float a0 = 0.f, a1 = 0.f, x00, x01;
            float2 t0, t1, t2, t3, t4;
            // dy=-4: far row sy=0 (taps at w-4, w, w+4)
            t0 = *(const float2*)(bp - 4 * SW - 4);
            t1 = *(const float2*)(bp - 4 * SW);
            t2 = *(const float2*)(bp - 4 * SW + 4);
            a0 += offF[0][0]*t0.x + offF[1][0]*t1.x + offF[2][0]*t2.x;
            a1 += offF[0][1]*t0.y + offF[1][1]*t1.y + offF[2][1]*t2.y;
            // dy=-2: near row sy=0 (taps at w-2, w, w+2)
            t0 = *(const float2*)(bp - 2 * SW - 2);
            t1 = *(const float2*)(bp - 2 * SW);
            t2 = *(const float2*)(bp - 2 * SW + 2);
            a0 += offN[0][0]*t0.x + offN[1][0]*t1.x + offN[2][0]*t2.x;
            a1 += offN[0][1]*t0.y + offN[1][1]*t1.y + offN[2][1]*t2.y;
            // dy=0: near+far sy=1, center
            t0 = *(const float2*)(bp - 4);
            t1 = *(const float2*)(bp - 2);
            t2 = *(const float2*)(bp);
            t3 = *(const float2*)(bp + 2);
            t4 = *(const float2*)(bp + 4);
            x00 = t2.x; x01 = t2.y;
            a0 += offN[3][0]*t1.x + offN[4][0]*t2.x + offN[5][0]*t3.x
                + offF[3][0]*t0.x + offF[4][0]*t2.x + offF[5][0]*t4.x;
            a1 += offN[3][1]*t1.y + offN[4][1]*t2.y + offN[5][1]*t3.y
                + offF[3][1]*t0.y + offF[4][1]*t2.y + offF[5][1]*t4.y;
            // dy=+2: near row sy=2
            t0 = *(const float2*)(bp + 2 * SW - 2);
            t1 = *(const float2*)(bp + 2 * SW);
            t2 = *(const float2*)(bp + 2 * SW + 2);
            a0 += offN[6][0]*t0.x + offN[7][0]*t1.x + offN[8][0]*t2.x;
            a1 += offN[6][1]*t0.y + offN[7][1]*t1.y + offN[8][1]*t2.y;
            // dy=+4: far row sy=2
            t0 = *(const float2*)(bp + 4 * SW - 4);
            t1 = *(const float2*)(bp + 4 * SW);
            t2 = *(const float2*)(bp + 4 * SW + 4);
            a0 += offF[6][0]*t0.x + offF[7][0]*t1.x + offF[8][0]*t2.x;
            a1 += offF[6][1]*t0.y + offF[7][1]*t1.y + offF[8][1]*t2.y;
            // epilogue (0.5 factor already folded into weights)
            float2 o;
            float x1a = fminf(fabsf(a0 - x00) * inv_scale, 4.0f);
            float x1b = fminf(fabsf(a1 - x01) * inv_scale, 4.0f);
            o.x = __builtin_amdgcn_rcpf(1.0f + __expf(-(4.0f - 2.0f * x1a)));
            o.y = __builtin_amdgcn_rcpf(1.0f + __expf(-(4.0f - 2.0f * x1b)));
            *(float2*)(outb + (size_t)(iv * DC + p) * HWc) = o;
        }
    };

    // Software pipeline, depth 2, statically indexed (pA/pB) via 2x unroll.
    // Trace: prologue leaves pA=iv1; it=0: issue pB=iv2, compute iv0,
    // commit pA(iv1)->sx[1]; then issue pA=iv3, compute iv1, commit
    // pB(iv2)->sx[0]; ... every commit consumes loads issued 2 phases ago.
    issue(pA, 0);
    commit(pA, sx[0]);                        // one-time cold-latency stall
    issue(pA, 1);
    bar();
    for (int it = 0; it < NIT; it += 2) {
        if (it + 2 < NIT) issue(pB, it + 2);
        compute(sx[0], it);
        commit(pA, sx[1]);                    // loads issued 2 phases ago
        bar();
        if (it + 3 < NIT) issue(pA, it + 3);
        compute(sx[1], it + 1);
        if (it + 2 < NIT) commit(pB, sx[0]);
        bar();
    }
}

extern "C" void kernel_launch(void* const* d_in, const int* in_sizes, int n_in,
                              void* d_out, int out_size, void* d_ws, size_t ws_size,
                              hipStream_t stream) {
    const float* ds   = (const float*)d_in[0];  // depth_sample [B,D,H,W]
    const float* dmin = (const float*)d_in[1];  // depth_min [B]
    const float* dmax = (const float*)d_in[2];  // depth_max [B]
    const float* off  = (const float*)d_in[3];  // offset [B,18,H,W]
    const float* sc   = (const float*)d_in[4];  // patchmatch_interval_scale
    float* out = (float*)d_out;                 // [B,D,H,W] fp32

    dim3 grid(NBLK, 1, 1);                      // flat; swizzled in-kernel
    dw_kernel<<<grid, NT, 0, stream>>>(ds, dmin, dmax, off, sc, out);
}

// Round 9
// 272.766 us; speedup vs baseline: 1.0737x; 1.0737x over previous
//
#include <hip/hip_runtime.h>

// Problem constants (fixed by setup_inputs)
constexpr int Bc = 2, Dc = 48, Hc = 512, Wc = 640;
constexpr int HWc = Hc * Wc;

// R0 geometry (best measured BW: 3.4 TB/s, 99.8us, BW-bound at its traffic)
// + R3's XCD-contiguous swizzle (traffic 287->88MB there). 64x16 tile,
// 256 threads, 4 consecutive-w pixels per thread, d split across 2 blocks.
constexpr int TW = 64, TH = 16, NT = 256;
constexpr int NXT = Wc / TW;                  // 10 tiles in w
constexpr int NYT = Hc / TH;                  // 32 tiles in h
constexpr int DSPLIT = 2;
constexpr int DCHUNK = Dc / DSPLIT;           // 24 planes per block
constexpr int NBLK = NXT * NYT * Bc * DSPLIT; // 1280 blocks = 5.0/CU
constexpr int NXCD = 8;
constexpr int BPX = NBLK / NXCD;              // 160 blocks per XCD
constexpr int HALO = 4;                       // far taps reach +/-4
constexpr int SW = TW + 2 * HALO;             // 72 (18 float4 per row)
constexpr int SH = TH + 2 * HALO;             // 24
constexpr int PLANE = SW * SH;                // 1728 floats/plane
constexpr int DC = 2;                         // d-planes per barrier interval
constexpr int NIT = DCHUNK / DC;              // 12 intervals
constexpr int NVEC = DC * PLANE / 4;          // 864 float4 per interval
constexpr int VPT = (NVEC + NT - 1) / NT;     // 4
constexpr int NSC = DC * PLANE;               // 3456 scalars per interval
constexpr int SPT = (NSC + NT - 1) / NT;      // 14

__device__ __forceinline__ int reflect_h(int h) {
    return h < 0 ? -h : (h >= Hc ? 2 * (Hc - 1) - h : h);
}
__device__ __forceinline__ int reflect_w(int w) {
    return w < 0 ? -w : (w >= Wc ? 2 * (Wc - 1) - w : w);
}

// LDS = 27.6 KB (5 blocks/CU would be 138KB <= 160); VGPR ~76 -> 4 blocks/CU
// resident (R0 measured: fine). NO waves-per-EU hint (R4: it forced spills).
// XCD-contiguous swizzle: hardware round-robins blockIdx%8 across XCDs;
// logical = (hw%8)*160 + hw/8 gives each XCD a contiguous 10x8-tile band
// (both d-chunks: dch is the innermost bit) -> halo lines and the offset
// tensor's second read hit the band's 4MB L2 instead of HBM.
__global__ __launch_bounds__(NT) void dw_kernel(
    const float* __restrict__ ds, const float* __restrict__ dmin,
    const float* __restrict__ dmax, const float* __restrict__ off,
    const float* __restrict__ scale_p, float* __restrict__ out)
{
    __shared__ float sx[2][DC * PLANE];       // double-buffered (27648 B)

    const int hw  = blockIdx.x;
    const int l   = (hw & (NXCD - 1)) * BPX + (hw >> 3);   // XCD-contiguous
    const int dch = l & 1;
    const int t   = l >> 1;
    const int bx  = t % NXT;
    const int rem = t / NXT;
    const int by  = rem % NYT;
    const int b   = rem / NYT;
    const int h0  = by * TH;
    const int w0  = bx * TW;
    const int tid  = threadIdx.x;
    const int col4 = tid & 15;                // 16 float4-groups across 64 w
    const int row  = tid >> 4;                // 0..15

    const float inv_min   = 1.0f / dmin[b];
    const float inv_max   = 1.0f / dmax[b];
    const float invd      = 1.0f / (inv_min - inv_max);
    const float nmc       = -inv_max * invd;  // x = fma(rcp(v), invd, nmc)
    const float inv_scale = 1.0f / scale_p[0];

    // 18 offset channels x 4 pixels -> 72 registers (float4 loads),
    // pre-scaled by 0.5 (folds (f+f1)*0.5 into the weights; reused 24x).
    float offF[9][4], offN[9][4];
    {
        const float* op = off + (size_t)b * 18 * HWc
                        + (size_t)(h0 + row) * Wc + (w0 + 4 * col4);
        #pragma unroll
        for (int s = 0; s < 9; ++s) {
            float4 vF = *(const float4*)(op + (size_t)s * HWc);
            float4 vN = *(const float4*)(op + (size_t)(s + 9) * HWc);
            offF[s][0] = 0.5f * vF.x; offF[s][1] = 0.5f * vF.y;
            offF[s][2] = 0.5f * vF.z; offF[s][3] = 0.5f * vF.w;
            offN[s][0] = 0.5f * vN.x; offN[s][1] = 0.5f * vN.y;
            offN[s][2] = 0.5f * vN.z; offN[s][3] = 0.5f * vN.w;
        }
    }

    const float* dsb  = ds  + ((size_t)b * Dc + dch * DCHUNK) * HWc;
    float*       outb = out + (size_t)b * Dc * HWc
                            + (size_t)(h0 + row) * Wc + (w0 + 4 * col4);
    const int dg0 = dch * DCHUNK;             // global d of this block's chunk

    // Stencil for one interval. Per plane: 15 ds_read_b128 feed 4 pixels.
    auto compute = [&](const float* sb, int dglob0) {
        #pragma unroll
        for (int p = 0; p < DC; ++p) {
            // base -> plane col 4*col4 == pixel col -4 (16B aligned)
            const float* base = sb + p * PLANE + (row + HALO) * SW + 4 * col4;
            float acc[4] = {0.f, 0.f, 0.f, 0.f};
            float x0[4], rb[12];
            auto ld12 = [&](const float* q) {
                *(float4*)(rb)     = *(const float4*)(q);
                *(float4*)(rb + 4) = *(const float4*)(q + 4);
                *(float4*)(rb + 8) = *(const float4*)(q + 8);
            };
            ld12(base - 4 * SW);              // dy=-4: far row sy=0
            #pragma unroll
            for (int j = 0; j < 4; ++j)
                acc[j] += offF[0][j]*rb[j] + offF[1][j]*rb[j+4] + offF[2][j]*rb[j+8];
            ld12(base - 2 * SW);              // dy=-2: near row sy=0
            #pragma unroll
            for (int j = 0; j < 4; ++j)
                acc[j] += offN[0][j]*rb[j+2] + offN[1][j]*rb[j+4] + offN[2][j]*rb[j+6];
            ld12(base);                       // dy=0: near+far sy=1, center
            #pragma unroll
            for (int j = 0; j < 4; ++j) {
                x0[j] = rb[j + 4];
                acc[j] += offN[3][j]*rb[j+2] + offN[4][j]*rb[j+4] + offN[5][j]*rb[j+6]
                        + offF[3][j]*rb[j]   + offF[4][j]*rb[j+4] + offF[5][j]*rb[j+8];
            }
            ld12(base + 2 * SW);              // dy=+2: near row sy=2
            #pragma unroll
            for (int j = 0; j < 4; ++j)
                acc[j] += offN[6][j]*rb[j+2] + offN[7][j]*rb[j+4] + offN[8][j]*rb[j+6];
            ld12(base + 4 * SW);              // dy=+4: far row sy=2
            #pragma unroll
            for (int j = 0; j < 4; ++j)
                acc[j] += offF[6][j]*rb[j] + offF[7][j]*rb[j+4] + offF[8][j]*rb[j+8];

            float4 o; float* po = (float*)&o;
            #pragma unroll
            for (int j = 0; j < 4; ++j) {
                // 0.5 factor already folded into weights
                float x1 = fminf(fabsf(acc[j] - x0[j]) * inv_scale, 4.0f);
                float tt = 4.0f - 2.0f * x1;
                po[j] = __builtin_amdgcn_rcpf(1.0f + __expf(-tt));
            }
            *(float4*)(outb + (size_t)(dglob0 + p) * HWc) = o;
        }
    };

    // w-reflect only touches first/last tile column; others vectorize.
    const bool interior = (bx > 0) && (bx + 1 < NXT);

    if (interior) {
        int vsrc[VPT];                        // d-invariant source offsets
        #pragma unroll
        for (int i = 0; i < VPT; ++i) {
            int vid = tid + i * NT;
            if (vid < NVEC) {
                int p    = vid / (PLANE / 4);
                int rem2 = vid - p * (PLANE / 4);
                int r    = rem2 / (SW / 4);
                int j    = rem2 - r * (SW / 4);
                int hs   = reflect_h(h0 + r - HALO);
                vsrc[i]  = p * HWc + hs * Wc + (w0 - HALO + 4 * j);
            } else vsrc[i] = 0;
        }
        float4 pre[VPT];
        auto issue = [&](int d0) {            // loads only -> in flight under compute
            const float* dp = dsb + (size_t)d0 * HWc;
            #pragma unroll
            for (int i = 0; i < VPT; ++i) {
                int vid = tid + i * NT;
                if (vid < NVEC) pre[i] = *(const float4*)(dp + vsrc[i]);
            }
        };
        auto commit = [&](float* sb) {
            #pragma unroll
            for (int i = 0; i < VPT; ++i) {
                int vid = tid + i * NT;
                if (vid < NVEC) {
                    float4 v = pre[i], x;
                    x.x = fmaf(__builtin_amdgcn_rcpf(v.x), invd, nmc);
                    x.y = fmaf(__builtin_amdgcn_rcpf(v.y), invd, nmc);
                    x.z = fmaf(__builtin_amdgcn_rcpf(v.z), invd, nmc);
                    x.w = fmaf(__builtin_amdgcn_rcpf(v.w), invd, nmc);
                    *(float4*)(sb + vid * 4) = x;
                }
            }
        };
        issue(0);
        commit(sx[0]);
        __syncthreads();
        for (int it = 0; it < NIT; ++it) {
            if (it + 1 < NIT) issue((it + 1) * DC);
            compute(sx[it & 1], dg0 + it * DC);
            if (it + 1 < NIT) commit(sx[(it + 1) & 1]);
            __syncthreads();
        }
    } else {
        int ssrc[SPT];                        // scalar path (w-edge blocks)
        #pragma unroll
        for (int i = 0; i < SPT; ++i) {
            int idx = tid + i * NT;
            if (idx < NSC) {
                int p    = idx / PLANE;
                int rem2 = idx - p * PLANE;
                int r    = rem2 / SW;
                int c    = rem2 - r * SW;
                int hs   = reflect_h(h0 + r - HALO);
                int ws   = reflect_w(w0 + c - HALO);
                ssrc[i]  = p * HWc + hs * Wc + ws;
            } else ssrc[i] = 0;
        }
        float pre[SPT];
        auto issue = [&](int d0) {
            const float* dp = dsb + (size_t)d0 * HWc;
            #pragma unroll
            for (int i = 0; i < SPT; ++i) {
                int idx = tid + i * NT;
                if (idx < NSC) pre[i] = dp[ssrc[i]];
            }
        };
        auto commit = [&](float* sb) {
            #pragma unroll
            for (int i = 0; i < SPT; ++i) {
                int idx = tid + i * NT;
                if (idx < NSC)
                    sb[idx] = fmaf(__builtin_amdgcn_rcpf(pre[i]), invd, nmc);
            }
        };
        issue(0);
        commit(sx[0]);
        __syncthreads();
        for (int it = 0; it < NIT; ++it) {
            if (it + 1 < NIT) issue((it + 1) * DC);
            compute(sx[it & 1], dg0 + it * DC);
            if (it + 1 < NIT) commit(sx[(it + 1) & 1]);
            __syncthreads();
        }
    }
}

extern "C" void kernel_launch(void* const* d_in, const int* in_sizes, int n_in,
                              void* d_out, int out_size, void* d_ws, size_t ws_size,
                              hipStream_t stream) {
    const float* ds   = (const float*)d_in[0];  // depth_sample [B,D,H,W]
    const float* dmin = (const float*)d_in[1];  // depth_min [B]
    const float* dmax = (const float*)d_in[2];  // depth_max [B]
    const float* off  = (const float*)d_in[3];  // offset [B,18,H,W]
    const float* sc   = (const float*)d_in[4];  // patchmatch_interval_scale
    float* out = (float*)d_out;                 // [B,D,H,W] fp32

    dim3 grid(NBLK, 1, 1);                      // flat; swizzled in-kernel
    dw_kernel<<<grid, NT, 0, stream>>>(ds, dmin, dmax, off, sc, out);
}